// Round 2
// baseline (925.706 us; speedup 1.0000x reference)
//
#include <hip/hip_runtime.h>
#include <math.h>

#define N_NODES 100000
#define N_EDGES 3200000
#define NEG 0.2f
#define NPB 128            // nodes per bucket
#define NB  782            // ceil(N_NODES / NPB)
#define LOG2E 1.442695041f

typedef __attribute__((ext_vector_type(8))) short short8;
typedef __attribute__((ext_vector_type(4))) float f32x4;
typedef __attribute__((ext_vector_type(2))) float f32x2;

__device__ __forceinline__ float lrelu(float x){ return x > 0.f ? x : NEG * x; }
__device__ __forceinline__ float bflo(unsigned int u){
  union { unsigned int i; float f; } v; v.i = u << 16; return v.f;
}
__device__ __forceinline__ float bfhi(unsigned int u){
  union { unsigned int i; float f; } v; v.i = u & 0xffff0000u; return v.f;
}
__device__ __forceinline__ unsigned short f2bf(float f){
  union { float f; unsigned int i; } v; v.f = f;
  unsigned int r = v.i + 0x7fffu + ((v.i >> 16) & 1u);
  return (unsigned short)(r >> 16);
}
__device__ __forceinline__ unsigned int packbf(float lo, float hi){
  return (unsigned int)f2bf(lo) | ((unsigned int)f2bf(hi) << 16);
}
// 4x fp32 -> packed OCP e4m3 dword (HW cvt, gfx950)
__device__ __forceinline__ unsigned int pk_fp8x4(float a, float b, float c, float d){
  int v = 0;
  v = __builtin_amdgcn_cvt_pk_fp8_f32(a, b, v, false);
  v = __builtin_amdgcn_cvt_pk_fp8_f32(c, d, v, true);
  return (unsigned int)v;
}
__device__ __forceinline__ f32x2 unpk_fp8_lo(unsigned int v){
  return __builtin_amdgcn_cvt_pk_f32_fp8((int)v, false);
}
__device__ __forceinline__ f32x2 unpk_fp8_hi(unsigned int v){
  return __builtin_amdgcn_cvt_pk_f32_fp8((int)v, true);
}
// packed dual-f32 FMA: acc.lo += a.lo*w.lo ; acc.hi += a.hi*w.hi
__device__ __forceinline__ void pk_fma(f32x2 &acc, f32x2 a, f32x2 w){
  asm("v_pk_fma_f32 %0, %1, %2, %0" : "+v"(acc) : "v"(a), "v"(w));
}
// weight: exp2(leaky_relu(t)) with t pre-scaled by log2e; fmax form is exact
__device__ __forceinline__ float wexp(float t){
  return __builtin_amdgcn_exp2f(fmaxf(t, NEG * t));
}

// ---- weight prep ----
__global__ void k_cvtW1(const float* __restrict__ W, unsigned short* __restrict__ Wt){
  int i = blockIdx.x*256 + threadIdx.x;
  if (i < 512*128){ int n = i >> 7, k = i & 127; Wt[i] = f2bf(W[k*512 + n]); }
}
__global__ void k_cvtW2(const float* __restrict__ W, unsigned short* __restrict__ Wt){
  int i = blockIdx.x*256 + threadIdx.x;
  if (i < 64*512){ int n = i >> 9, k = i & 511; Wt[i] = f2bf(W[k*64 + n]); }
}

// ---- GEMM1 (MFMA) + fused layer-1 scores; feat1 stored as fp8 e4m3 ----
__global__ __launch_bounds__(256) void k_mm1(const float* __restrict__ A,
    const unsigned short* __restrict__ Bt,
    unsigned char* __restrict__ C8, int M,
    const float* __restrict__ al, const float* __restrict__ ar,
    float* __restrict__ el, float* __restrict__ er){
  __shared__ unsigned short sm[18432];          // As 128x72 | Bs 128x72 (36.9 KB)
  unsigned short* As = sm;
  unsigned short* Bs = sm + 9216;
  const int t = threadIdx.x;
  const int w = t >> 6, l = t & 63;
  const int quad = l >> 4, l16 = l & 15;
  const int m0 = blockIdx.x * 128;
  const int head = blockIdx.y;
  const int moff = (w & 1) * 64, noff = (w >> 1) * 64;
  f32x4 acc[4][4];
  #pragma unroll
  for (int i=0;i<4;++i)
    #pragma unroll
    for (int j=0;j<4;++j){ acc[i][j][0]=0.f; acc[i][j][1]=0.f; acc[i][j][2]=0.f; acc[i][j][3]=0.f; }
  for (int kb = 0; kb < 2; ++kb){
    const int K0 = kb * 64;
    #pragma unroll
    for (int i=0;i<8;++i){              // A: 128x64 fp32 -> bf16 LDS
      int idx = t + i*256;
      int row = idx >> 4, c4 = (idx & 15) * 4;
      float4 v = make_float4(0.f,0.f,0.f,0.f);
      if (m0 + row < M) v = *(const float4*)(A + (size_t)(m0+row)*128 + K0 + c4);
      uint2 p; p.x = packbf(v.x, v.y); p.y = packbf(v.z, v.w);
      *(uint2*)(As + row*72 + c4) = p;
    }
    #pragma unroll
    for (int i=0;i<4;++i){              // B: 128x64 bf16 copy
      int idx = t + i*256;
      int row = idx >> 3, c8 = (idx & 7) * 8;
      *(uint4*)(Bs + row*72 + c8) =
        *(const uint4*)(Bt + (size_t)(head*128 + row)*128 + K0 + c8);
    }
    __syncthreads();
    #pragma unroll
    for (int ks = 0; ks < 2; ++ks){
      short8 af[4], bfr[4];
      #pragma unroll
      for (int mi=0; mi<4; ++mi)
        af[mi] = *(const short8*)(As + (moff + mi*16 + l16)*72 + ks*32 + quad*8);
      #pragma unroll
      for (int ni=0; ni<4; ++ni)
        bfr[ni] = *(const short8*)(Bs + (noff + ni*16 + l16)*72 + ks*32 + quad*8);
      #pragma unroll
      for (int mi=0; mi<4; ++mi)
        #pragma unroll
        for (int ni=0; ni<4; ++ni)
          acc[mi][ni] = __builtin_amdgcn_mfma_f32_16x16x32_bf16(af[mi], bfr[ni], acc[mi][ni], 0,0,0);
    }
    __syncthreads();
  }
  // epilogue: bf16 repack via LDS (exact values for scores), fp8 global store
  unsigned short* Cs = sm;                       // 128x136 bf16 (34.8 KB)
  #pragma unroll
  for (int mi=0; mi<4; ++mi)
    #pragma unroll
    for (int ni=0; ni<4; ++ni){
      int col = noff + ni*16 + l16;
      int rb  = moff + mi*16 + quad*4;
      #pragma unroll
      for (int r=0;r<4;++r) Cs[(rb+r)*136 + col] = f2bf(acc[mi][ni][r]);
    }
  __syncthreads();
  const int hcol = head * 128;
  #pragma unroll
  for (int i=0;i<8;++i){                // 128 rows x 128 cols, 8 fp8/thread/iter
    int e = t + i*256;
    int row = e >> 4, c8 = (e & 15) * 8;
    uint4 qb = *(const uint4*)(Cs + row*136 + c8);
    uint2 o;
    o.x = pk_fp8x4(bflo(qb.x), bfhi(qb.x), bflo(qb.y), bfhi(qb.y));
    o.y = pk_fp8x4(bflo(qb.z), bfhi(qb.z), bflo(qb.w), bfhi(qb.w));
    if (m0 + row < M)
      *(uint2*)(C8 + (size_t)(m0+row)*512 + hcol + c8) = o;
  }
  // fused scores: thread pair (t, t^1) covers one row (64 cols each)
  {
    int row = t >> 1, half = t & 1;
    const float* alp = al + head*128 + half*64;
    const float* arp = ar + head*128 + half*64;
    const unsigned short* cp = Cs + row*136 + half*64;
    float se = 0.f, sr = 0.f;
    #pragma unroll
    for (int i=0;i<8;++i){
      uint4 q = *(const uint4*)(cp + i*8);
      float4 a0 = *(const float4*)(alp + i*8), a1 = *(const float4*)(alp + i*8 + 4);
      float4 r0 = *(const float4*)(arp + i*8), r1 = *(const float4*)(arp + i*8 + 4);
      se += bflo(q.x)*a0.x + bfhi(q.x)*a0.y + bflo(q.y)*a0.z + bfhi(q.y)*a0.w
          + bflo(q.z)*a1.x + bfhi(q.z)*a1.y + bflo(q.w)*a1.z + bfhi(q.w)*a1.w;
      sr += bflo(q.x)*r0.x + bfhi(q.x)*r0.y + bflo(q.y)*r0.z + bfhi(q.y)*r0.w
          + bflo(q.z)*r1.x + bfhi(q.z)*r1.y + bflo(q.w)*r1.z + bfhi(q.w)*r1.w;
    }
    se += __shfl_xor(se, 1); sr += __shfl_xor(sr, 1);
    if (half == 0 && m0 + row < M){
      el[(m0+row)*4 + head] = se * LOG2E;   // pre-scale for exp2 weights
      er[(m0+row)*4 + head] = sr * LOG2E;
    }
  }
}

// ---- GEMM2 (MFMA) + fused layer-2 scores ----
__global__ __launch_bounds__(256) void k_mm2(const unsigned short* __restrict__ A,
    const unsigned short* __restrict__ Bt,
    unsigned short* __restrict__ C, int M,
    const float* __restrict__ al, const float* __restrict__ ar,
    float* __restrict__ el, float* __restrict__ er){
  __shared__ unsigned short sm[13824];          // As 128x72 | Bs 64x72 (27.6 KB)
  unsigned short* As = sm;
  unsigned short* Bs = sm + 9216;
  const int t = threadIdx.x;
  const int w = t >> 6, l = t & 63;
  const int quad = l >> 4, l16 = l & 15;
  const int m0 = blockIdx.x * 128;
  const int moff = w * 32;
  f32x4 acc[2][4];
  #pragma unroll
  for (int i=0;i<2;++i)
    #pragma unroll
    for (int j=0;j<4;++j){ acc[i][j][0]=0.f; acc[i][j][1]=0.f; acc[i][j][2]=0.f; acc[i][j][3]=0.f; }
  for (int kb = 0; kb < 8; ++kb){
    const int K0 = kb * 64;
    #pragma unroll
    for (int i=0;i<4;++i){
      int idx = t + i*256;
      int row = idx >> 3, c8 = (idx & 7) * 8;
      uint4 v; v.x=0u; v.y=0u; v.z=0u; v.w=0u;
      if (m0 + row < M) v = *(const uint4*)(A + (size_t)(m0+row)*512 + K0 + c8);
      *(uint4*)(As + row*72 + c8) = v;
    }
    #pragma unroll
    for (int i=0;i<2;++i){
      int idx = t + i*256;
      int row = idx >> 3, c8 = (idx & 7) * 8;
      *(uint4*)(Bs + row*72 + c8) = *(const uint4*)(Bt + (size_t)row*512 + K0 + c8);
    }
    __syncthreads();
    #pragma unroll
    for (int ks = 0; ks < 2; ++ks){
      short8 af[2], bfr[4];
      #pragma unroll
      for (int mi=0; mi<2; ++mi)
        af[mi] = *(const short8*)(As + (moff + mi*16 + l16)*72 + ks*32 + quad*8);
      #pragma unroll
      for (int ni=0; ni<4; ++ni)
        bfr[ni] = *(const short8*)(Bs + (ni*16 + l16)*72 + ks*32 + quad*8);
      #pragma unroll
      for (int mi=0; mi<2; ++mi)
        #pragma unroll
        for (int ni=0; ni<4; ++ni)
          acc[mi][ni] = __builtin_amdgcn_mfma_f32_16x16x32_bf16(af[mi], bfr[ni], acc[mi][ni], 0,0,0);
    }
    __syncthreads();
  }
  unsigned short* Cs = sm;                       // 128x72 bf16
  #pragma unroll
  for (int mi=0; mi<2; ++mi)
    #pragma unroll
    for (int ni=0; ni<4; ++ni){
      int col = ni*16 + l16;
      int rb  = moff + mi*16 + quad*4;
      #pragma unroll
      for (int r=0;r<4;++r) Cs[(rb+r)*72 + col] = f2bf(acc[mi][ni][r]);
    }
  __syncthreads();
  #pragma unroll
  for (int i=0;i<4;++i){
    int e = t + i*256;
    int row = e >> 3, c8 = (e & 7) * 8;
    if (m0 + row < M)
      *(uint4*)(C + (size_t)(m0+row)*64 + c8) = *(const uint4*)(Cs + row*72 + c8);
  }
  // fused scores: thread pair covers one row (32 cols each)
  {
    int row = t >> 1, half = t & 1;
    const float* alp = al + half*32;
    const float* arp = ar + half*32;
    const unsigned short* cp = Cs + row*72 + half*32;
    float se = 0.f, sr = 0.f;
    #pragma unroll
    for (int i=0;i<4;++i){
      uint4 q = *(const uint4*)(cp + i*8);
      float4 a0 = *(const float4*)(alp + i*8), a1 = *(const float4*)(alp + i*8 + 4);
      float4 r0 = *(const float4*)(arp + i*8), r1 = *(const float4*)(arp + i*8 + 4);
      se += bflo(q.x)*a0.x + bfhi(q.x)*a0.y + bflo(q.y)*a0.z + bfhi(q.y)*a0.w
          + bflo(q.z)*a1.x + bfhi(q.z)*a1.y + bflo(q.w)*a1.z + bfhi(q.w)*a1.w;
      sr += bflo(q.x)*r0.x + bfhi(q.x)*r0.y + bflo(q.y)*r0.z + bfhi(q.y)*r0.w
          + bflo(q.z)*r1.x + bfhi(q.z)*r1.y + bflo(q.w)*r1.z + bfhi(q.w)*r1.w;
    }
    se += __shfl_xor(se, 1); sr += __shfl_xor(sr, 1);
    if (half == 0 && m0 + row < M){
      el[m0+row] = se * LOG2E;   // pre-scale for exp2 weights
      er[m0+row] = sr * LOG2E;
    }
  }
}

// ---- bucketed CSR build ----
__global__ void k_zero(int* __restrict__ p, int n){
  int i = blockIdx.x*blockDim.x + threadIdx.x;
  if (i < n) p[i] = 0;
}
__global__ void k_bcount(const int* __restrict__ dst, int* __restrict__ bcnt){
  int e = blockIdx.x*blockDim.x + threadIdx.x;
  if (e < N_EDGES) atomicAdd(&bcnt[(dst[e] >> 7) * 16], 1);
}
__global__ __launch_bounds__(1024) void k_bscan(const int* __restrict__ bcnt,
    int* __restrict__ bbase, int* __restrict__ bcur){
  __shared__ int lds[1024];
  int t = threadIdx.x;
  int v = (t < NB) ? bcnt[t*16] : 0;
  lds[t] = v; __syncthreads();
  for (int off=1; off<1024; off<<=1){
    int u = (t>=off)? lds[t-off] : 0;
    __syncthreads();
    lds[t] += u;
    __syncthreads();
  }
  if (t < NB){
    int ex = lds[t] - v;            // exclusive prefix
    bbase[t] = ex;
    bcur[t*16] = ex;
  }
  if (t == 0) bbase[NB] = N_EDGES;
}
__global__ void k_bucket(const int* __restrict__ src, const int* __restrict__ dst,
                         int* __restrict__ bcur, int* __restrict__ staged){
  int e = blockIdx.x*blockDim.x + threadIdx.x;
  if (e < N_EDGES){
    int d = dst[e];
    int b = d >> 7;
    int pos = atomicAdd(&bcur[b*16], 1);
    staged[pos] = (src[e] << 7) | (d & (NPB-1));
  }
}
__global__ __launch_bounds__(256) void k_binsort(const int* __restrict__ staged,
    const int* __restrict__ bbase, int* __restrict__ csr_src,
    int* __restrict__ indptr){
  __shared__ int hist[NPB];
  __shared__ int scan[NPB];
  __shared__ int lcur[NPB];
  const int b = blockIdx.x, t = threadIdx.x;
  const int base = bbase[b], end = bbase[b+1];
  if (t < NPB) hist[t] = 0;
  __syncthreads();
  for (int i = base + t; i < end; i += 256)
    atomicAdd(&hist[staged[i] & (NPB-1)], 1);
  __syncthreads();
  int v = (t < NPB) ? hist[t] : 0;
  if (t < NPB) scan[t] = v;
  __syncthreads();
  for (int off=1; off<NPB; off<<=1){
    int u = (t < NPB && t >= off) ? scan[t-off] : 0;
    __syncthreads();
    if (t < NPB) scan[t] += u;
    __syncthreads();
  }
  const int node0 = b * NPB;
  if (t < NPB){
    int ex = base + scan[t] - v;    // global exclusive offset for node0+t
    lcur[t] = ex;
    if (node0 + t < N_NODES) indptr[node0 + t] = ex;
  }
  if (b == NB-1 && t == 0) indptr[N_NODES] = N_EDGES;
  __syncthreads();
  for (int i = base + t; i < end; i += 256){
    int pv = staged[i];
    int pos = atomicAdd(&lcur[pv & (NPB-1)], 1);
    csr_src[pos] = pv >> 7;
  }
}

// ---- layer-2 per-edge weight precompute (1 lane per edge, no redundancy) ----
__global__ __launch_bounds__(256) void k_w2(const float* __restrict__ el,
    const float* __restrict__ er, const int* __restrict__ indptr,
    const int* __restrict__ csr_src, float* __restrict__ w2){
  int wave = threadIdx.x >> 6, lane = threadIdx.x & 63;
  int n = blockIdx.x*4 + wave;
  if (n >= N_NODES) return;
  int p0 = indptr[n], p1 = indptr[n+1];
  float ern = er[n];
  for (int e = p0 + lane; e < p1; e += 64)
    w2[e] = wexp(el[csr_src[e]] + ern);
}

// ---- layer-1 aggregate + ELU: one-pass softmax, wave per node, pk_fma ----
__global__ __launch_bounds__(256) void k_agg1(const unsigned char* __restrict__ feat,
    const float* __restrict__ el, const float* __restrict__ er,
    const int* __restrict__ indptr, const int* __restrict__ csr_src,
    unsigned short* __restrict__ out){
  int wave = threadIdx.x >> 6, lane = threadIdx.x & 63;
  int n = blockIdx.x*4 + wave;
  if (n >= N_NODES) return;
  int p0 = indptr[n], p1 = indptr[n+1];
  const int hh = lane >> 4;
  const unsigned d0 = lane * 8u;
  const float myer = er[n*4 + hh];
  float ssum = 0.f;
  f32x2 acc[4];
  #pragma unroll
  for (int i=0;i<4;++i){ acc[i][0]=0.f; acc[i][1]=0.f; }
  int e = p0;
  for (; e + 1 < p1; e += 2){
    int s0 = csr_src[e], s1 = csr_src[e+1];
    float t0 = el[(s0<<2) + hh] + myer;
    float t1 = el[(s1<<2) + hh] + myer;
    uint2 q0 = *(const uint2*)(feat + (((unsigned)s0) << 9) + d0);
    uint2 q1 = *(const uint2*)(feat + (((unsigned)s1) << 9) + d0);
    float w0 = wexp(t0);
    float w1 = wexp(t1);
    ssum += w0 + w1;
    f32x2 W0; W0[0]=w0; W0[1]=w0;
    f32x2 W1; W1[0]=w1; W1[1]=w1;
    pk_fma(acc[0], unpk_fp8_lo(q0.x), W0); pk_fma(acc[0], unpk_fp8_lo(q1.x), W1);
    pk_fma(acc[1], unpk_fp8_hi(q0.x), W0); pk_fma(acc[1], unpk_fp8_hi(q1.x), W1);
    pk_fma(acc[2], unpk_fp8_lo(q0.y), W0); pk_fma(acc[2], unpk_fp8_lo(q1.y), W1);
    pk_fma(acc[3], unpk_fp8_hi(q0.y), W0); pk_fma(acc[3], unpk_fp8_hi(q1.y), W1);
  }
  if (e < p1){
    int s0 = csr_src[e];
    float t0 = el[(s0<<2) + hh] + myer;
    uint2 q0 = *(const uint2*)(feat + (((unsigned)s0) << 9) + d0);
    float w0 = wexp(t0);
    ssum += w0;
    f32x2 W0; W0[0]=w0; W0[1]=w0;
    pk_fma(acc[0], unpk_fp8_lo(q0.x), W0);
    pk_fma(acc[1], unpk_fp8_hi(q0.x), W0);
    pk_fma(acc[2], unpk_fp8_lo(q0.y), W0);
    pk_fma(acc[3], unpk_fp8_hi(q0.y), W0);
  }
  float inv = ssum > 0.f ? 1.f/ssum : 0.f;
  float o8[8] = {acc[0][0],acc[0][1],acc[1][0],acc[1][1],
                 acc[2][0],acc[2][1],acc[3][0],acc[3][1]};
  #pragma unroll
  for (int i=0;i<8;++i){
    float v = o8[i] * inv;
    o8[i] = v > 0.f ? v : __expf(v) - 1.f;   // fused ELU
  }
  uint4 o;
  o.x = packbf(o8[0],o8[1]); o.y = packbf(o8[2],o8[3]);
  o.z = packbf(o8[4],o8[5]); o.w = packbf(o8[6],o8[7]);
  *(uint4*)(out + (size_t)n*512 + d0) = o;
}

// ---- layer-2 aggregate: precomputed weights, pk_fma, eighth-wave per edge ----
__global__ __launch_bounds__(256) void k_agg2(const unsigned short* __restrict__ feat,
    const float* __restrict__ w2, const float* __restrict__ er,
    const int* __restrict__ indptr, const int* __restrict__ csr_src,
    float* __restrict__ out){
  int wave = threadIdx.x >> 6, lane = threadIdx.x & 63;
  int n = blockIdx.x*4 + wave;
  if (n >= N_NODES) return;
  int p0 = indptr[n], p1 = indptr[n+1];
  int g = lane >> 3, ql = lane & 7;
  float s = 0.f;
  f32x2 acc[4];
  #pragma unroll
  for (int i=0;i<4;++i){ acc[i][0]=0.f; acc[i][1]=0.f; }
  for (int e = p0 + g; e < p1; e += 8){
    int si = csr_src[e];
    float w = w2[e];
    uint4 v = *(const uint4*)(feat + (size_t)si*64 + ql*8);
    s += w;
    f32x2 W; W[0]=w; W[1]=w;
    f32x2 a;
    a[0]=bflo(v.x); a[1]=bfhi(v.x); pk_fma(acc[0], a, W);
    a[0]=bflo(v.y); a[1]=bfhi(v.y); pk_fma(acc[1], a, W);
    a[0]=bflo(v.z); a[1]=bfhi(v.z); pk_fma(acc[2], a, W);
    a[0]=bflo(v.w); a[1]=bfhi(v.w); pk_fma(acc[3], a, W);
  }
  #pragma unroll
  for (int m=8;m<64;m<<=1){
    s += __shfl_xor(s,m);
    #pragma unroll
    for (int i=0;i<4;++i){
      acc[i][0] += __shfl_xor(acc[i][0],m);
      acc[i][1] += __shfl_xor(acc[i][1],m);
    }
  }
  float inv = s > 0.f ? 1.f/s : 0.f;
  if (g == 0){
    float* op = out + (size_t)n*64 + ql*8;
    *(float4*)op     = make_float4(acc[0][0]*inv, acc[0][1]*inv, acc[1][0]*inv, acc[1][1]*inv);
    *(float4*)(op+4) = make_float4(acc[2][0]*inv, acc[2][1]*inv, acc[3][0]*inv, acc[3][1]*inv);
  }
}

extern "C" void kernel_launch(void* const* d_in, const int* in_sizes, int n_in,
                              void* d_out, int out_size, void* d_ws, size_t ws_size,
                              hipStream_t stream){
  const float* x   = (const float*)d_in[0];
  const float* W1  = (const float*)d_in[1];
  const float* al1 = (const float*)d_in[2];
  const float* ar1 = (const float*)d_in[3];
  const float* W2  = (const float*)d_in[4];
  const float* al2 = (const float*)d_in[5];
  const float* ar2 = (const float*)d_in[6];
  const int* src   = (const int*)d_in[7];
  const int* dst   = (const int*)d_in[8];
  float* out = (float*)d_out;

  char* ws = (char*)d_ws;
  size_t off = 0;
  auto alloc = [&](size_t bytes)->char*{
    char* p = ws + off; off += (bytes + 255) & ~(size_t)255; return p;
  };
  unsigned char*  feat1 = (unsigned char*)alloc((size_t)N_NODES*512);     // 51.2 MB fp8
  unsigned short* h1    = (unsigned short*)alloc((size_t)N_NODES*512*2);  // 102.4 MB
  unsigned short* feat2b = (unsigned short*)feat1;  // alias: feat1 dead after k_agg1
  unsigned short* W1t = (unsigned short*)alloc(512*128*2);
  unsigned short* W2t = (unsigned short*)alloc(64*512*2);
  float* el1 = (float*)alloc((size_t)N_NODES*4*4);
  float* er1 = (float*)alloc((size_t)N_NODES*4*4);
  float* el2 = el1;                           // alias: el1 dead after k_agg1
  float* er2 = er1;
  int* bcnt    = (int*)alloc((size_t)NB*16*4);        // padded: 1 counter / 64B
  int* bcur    = (int*)alloc((size_t)NB*16*4);
  int* bbase   = (int*)alloc((size_t)(NB+1)*4);
  int* indptr  = (int*)alloc((size_t)(N_NODES+1)*4);
  int* staged  = (int*)alloc((size_t)N_EDGES*4);                          // 12.8 MB
  int* csr_src = (int*)alloc((size_t)N_EDGES*4);                          // 12.8 MB
  float* w2arr = (float*)alloc((size_t)N_EDGES*4);                        // 12.8 MB
  // total ~196 MB (< proven 222 MB footprint)

  dim3 b256(256);
  k_zero<<<dim3((NB*16+255)/256), b256, 0, stream>>>(bcnt, NB*16);
  k_cvtW1<<<dim3(256), b256, 0, stream>>>(W1, W1t);
  k_cvtW2<<<dim3(128), b256, 0, stream>>>(W2, W2t);
  // layer 1 projection (MFMA) + fused scores; feat1 -> fp8
  k_mm1<<<dim3(782, 4), b256, 0, stream>>>(x, W1t, feat1, N_NODES, al1, ar1, el1, er1);
  // bucketed dst-CSR: bucket-count -> scan -> bucket-scatter -> per-bucket sort
  k_bcount<<<dim3((N_EDGES+255)/256), b256, 0, stream>>>(dst, bcnt);
  k_bscan<<<dim3(1), dim3(1024), 0, stream>>>(bcnt, bbase, bcur);
  k_bucket<<<dim3((N_EDGES+255)/256), b256, 0, stream>>>(src, dst, bcur, staged);
  k_binsort<<<dim3(NB), b256, 0, stream>>>(staged, bbase, csr_src, indptr);
  // layer-1 aggregate + ELU (single-pass, fp8 gather)
  k_agg1<<<dim3(25000), b256, 0, stream>>>(feat1, el1, er1, indptr, csr_src, h1);
  // layer 2 (MFMA) + fused scores
  k_mm2<<<dim3(782), b256, 0, stream>>>(h1, W2t, feat2b, N_NODES, al2, ar2, el2, er2);
  // layer-2 weights then aggregate
  k_w2<<<dim3(25000), b256, 0, stream>>>(el2, er2, indptr, csr_src, w2arr);
  k_agg2<<<dim3(25000), b256, 0, stream>>>(feat2b, w2arr, er2, indptr, csr_src, out);
}

// Round 3
// 895.690 us; speedup vs baseline: 1.0335x; 1.0335x over previous
//
#include <hip/hip_runtime.h>
#include <math.h>

#define N_NODES 100000
#define N_EDGES 3200000
#define NEG 0.2f
#define NPB 128            // nodes per bucket
#define NB  782            // ceil(N_NODES / NPB)
#define LOG2E 1.442695041f

typedef __attribute__((ext_vector_type(8))) short short8;
typedef __attribute__((ext_vector_type(4))) float f32x4;
typedef __attribute__((ext_vector_type(2))) float f32x2;

__device__ __forceinline__ float lrelu(float x){ return x > 0.f ? x : NEG * x; }
__device__ __forceinline__ float bflo(unsigned int u){
  union { unsigned int i; float f; } v; v.i = u << 16; return v.f;
}
__device__ __forceinline__ float bfhi(unsigned int u){
  union { unsigned int i; float f; } v; v.i = u & 0xffff0000u; return v.f;
}
__device__ __forceinline__ unsigned short f2bf(float f){
  union { float f; unsigned int i; } v; v.f = f;
  unsigned int r = v.i + 0x7fffu + ((v.i >> 16) & 1u);
  return (unsigned short)(r >> 16);
}
__device__ __forceinline__ unsigned int packbf(float lo, float hi){
  return (unsigned int)f2bf(lo) | ((unsigned int)f2bf(hi) << 16);
}
// 4x fp32 -> packed OCP e4m3 dword (HW cvt, gfx950)
__device__ __forceinline__ unsigned int pk_fp8x4(float a, float b, float c, float d){
  int v = 0;
  v = __builtin_amdgcn_cvt_pk_fp8_f32(a, b, v, false);
  v = __builtin_amdgcn_cvt_pk_fp8_f32(c, d, v, true);
  return (unsigned int)v;
}
__device__ __forceinline__ f32x2 unpk_fp8_lo(unsigned int v){
  return __builtin_amdgcn_cvt_pk_f32_fp8((int)v, false);
}
__device__ __forceinline__ f32x2 unpk_fp8_hi(unsigned int v){
  return __builtin_amdgcn_cvt_pk_f32_fp8((int)v, true);
}
// packed dual-f32 FMA: acc.lo += a.lo*w.lo ; acc.hi += a.hi*w.hi
__device__ __forceinline__ void pk_fma(f32x2 &acc, f32x2 a, f32x2 w){
  asm("v_pk_fma_f32 %0, %1, %2, %0" : "+v"(acc) : "v"(a), "v"(w));
}
// weight: exp2(leaky_relu(t)) with t pre-scaled by log2e; fmax form is exact
__device__ __forceinline__ float wexp(float t){
  return __builtin_amdgcn_exp2f(fmaxf(t, NEG * t));
}

// ---- weight prep ----
__global__ void k_cvtW1(const float* __restrict__ W, unsigned short* __restrict__ Wt){
  int i = blockIdx.x*256 + threadIdx.x;
  if (i < 512*128){ int n = i >> 7, k = i & 127; Wt[i] = f2bf(W[k*512 + n]); }
}
__global__ void k_cvtW2(const float* __restrict__ W, unsigned short* __restrict__ Wt){
  int i = blockIdx.x*256 + threadIdx.x;
  if (i < 64*512){ int n = i >> 9, k = i & 511; Wt[i] = f2bf(W[k*64 + n]); }
}

// ---- GEMM1 (MFMA) + fused layer-1 scores; feat1 stored as fp8 e4m3 ----
__global__ __launch_bounds__(256) void k_mm1(const float* __restrict__ A,
    const unsigned short* __restrict__ Bt,
    unsigned char* __restrict__ C8, int M,
    const float* __restrict__ al, const float* __restrict__ ar,
    float* __restrict__ el, float* __restrict__ er){
  __shared__ unsigned short sm[18432];          // As 128x72 | Bs 128x72 (36.9 KB)
  unsigned short* As = sm;
  unsigned short* Bs = sm + 9216;
  const int t = threadIdx.x;
  const int w = t >> 6, l = t & 63;
  const int quad = l >> 4, l16 = l & 15;
  const int m0 = blockIdx.x * 128;
  const int head = blockIdx.y;
  const int moff = (w & 1) * 64, noff = (w >> 1) * 64;
  f32x4 acc[4][4];
  #pragma unroll
  for (int i=0;i<4;++i)
    #pragma unroll
    for (int j=0;j<4;++j){ acc[i][j][0]=0.f; acc[i][j][1]=0.f; acc[i][j][2]=0.f; acc[i][j][3]=0.f; }
  for (int kb = 0; kb < 2; ++kb){
    const int K0 = kb * 64;
    #pragma unroll
    for (int i=0;i<8;++i){              // A: 128x64 fp32 -> bf16 LDS
      int idx = t + i*256;
      int row = idx >> 4, c4 = (idx & 15) * 4;
      float4 v = make_float4(0.f,0.f,0.f,0.f);
      if (m0 + row < M) v = *(const float4*)(A + (size_t)(m0+row)*128 + K0 + c4);
      uint2 p; p.x = packbf(v.x, v.y); p.y = packbf(v.z, v.w);
      *(uint2*)(As + row*72 + c4) = p;
    }
    #pragma unroll
    for (int i=0;i<4;++i){              // B: 128x64 bf16 copy
      int idx = t + i*256;
      int row = idx >> 3, c8 = (idx & 7) * 8;
      *(uint4*)(Bs + row*72 + c8) =
        *(const uint4*)(Bt + (size_t)(head*128 + row)*128 + K0 + c8);
    }
    __syncthreads();
    #pragma unroll
    for (int ks = 0; ks < 2; ++ks){
      short8 af[4], bfr[4];
      #pragma unroll
      for (int mi=0; mi<4; ++mi)
        af[mi] = *(const short8*)(As + (moff + mi*16 + l16)*72 + ks*32 + quad*8);
      #pragma unroll
      for (int ni=0; ni<4; ++ni)
        bfr[ni] = *(const short8*)(Bs + (noff + ni*16 + l16)*72 + ks*32 + quad*8);
      #pragma unroll
      for (int mi=0; mi<4; ++mi)
        #pragma unroll
        for (int ni=0; ni<4; ++ni)
          acc[mi][ni] = __builtin_amdgcn_mfma_f32_16x16x32_bf16(af[mi], bfr[ni], acc[mi][ni], 0,0,0);
    }
    __syncthreads();
  }
  // epilogue: bf16 repack via LDS (exact values for scores), fp8 global store
  unsigned short* Cs = sm;                       // 128x136 bf16 (34.8 KB)
  #pragma unroll
  for (int mi=0; mi<4; ++mi)
    #pragma unroll
    for (int ni=0; ni<4; ++ni){
      int col = noff + ni*16 + l16;
      int rb  = moff + mi*16 + quad*4;
      #pragma unroll
      for (int r=0;r<4;++r) Cs[(rb+r)*136 + col] = f2bf(acc[mi][ni][r]);
    }
  __syncthreads();
  const int hcol = head * 128;
  #pragma unroll
  for (int i=0;i<8;++i){                // 128 rows x 128 cols, 8 fp8/thread/iter
    int e = t + i*256;
    int row = e >> 4, c8 = (e & 15) * 8;
    uint4 qb = *(const uint4*)(Cs + row*136 + c8);
    uint2 o;
    o.x = pk_fp8x4(bflo(qb.x), bfhi(qb.x), bflo(qb.y), bfhi(qb.y));
    o.y = pk_fp8x4(bflo(qb.z), bfhi(qb.z), bflo(qb.w), bfhi(qb.w));
    if (m0 + row < M)
      *(uint2*)(C8 + (size_t)(m0+row)*512 + hcol + c8) = o;
  }
  // fused scores: thread pair (t, t^1) covers one row (64 cols each)
  {
    int row = t >> 1, half = t & 1;
    const float* alp = al + head*128 + half*64;
    const float* arp = ar + head*128 + half*64;
    const unsigned short* cp = Cs + row*136 + half*64;
    float se = 0.f, sr = 0.f;
    #pragma unroll
    for (int i=0;i<8;++i){
      uint4 q = *(const uint4*)(cp + i*8);
      float4 a0 = *(const float4*)(alp + i*8), a1 = *(const float4*)(alp + i*8 + 4);
      float4 r0 = *(const float4*)(arp + i*8), r1 = *(const float4*)(arp + i*8 + 4);
      se += bflo(q.x)*a0.x + bfhi(q.x)*a0.y + bflo(q.y)*a0.z + bfhi(q.y)*a0.w
          + bflo(q.z)*a1.x + bfhi(q.z)*a1.y + bflo(q.w)*a1.z + bfhi(q.w)*a1.w;
      sr += bflo(q.x)*r0.x + bfhi(q.x)*r0.y + bflo(q.y)*r0.z + bfhi(q.y)*r0.w
          + bflo(q.z)*r1.x + bfhi(q.z)*r1.y + bflo(q.w)*r1.z + bfhi(q.w)*r1.w;
    }
    se += __shfl_xor(se, 1); sr += __shfl_xor(sr, 1);
    if (half == 0 && m0 + row < M){
      el[(m0+row)*4 + head] = se * LOG2E;   // pre-scale for exp2 weights
      er[(m0+row)*4 + head] = sr * LOG2E;
    }
  }
}

// ---- GEMM2 (MFMA) + fused layer-2 scores ----
__global__ __launch_bounds__(256) void k_mm2(const unsigned short* __restrict__ A,
    const unsigned short* __restrict__ Bt,
    unsigned short* __restrict__ C, int M,
    const float* __restrict__ al, const float* __restrict__ ar,
    float* __restrict__ el, float* __restrict__ er){
  __shared__ unsigned short sm[13824];          // As 128x72 | Bs 64x72 (27.6 KB)
  unsigned short* As = sm;
  unsigned short* Bs = sm + 9216;
  const int t = threadIdx.x;
  const int w = t >> 6, l = t & 63;
  const int quad = l >> 4, l16 = l & 15;
  const int m0 = blockIdx.x * 128;
  const int moff = w * 32;
  f32x4 acc[2][4];
  #pragma unroll
  for (int i=0;i<2;++i)
    #pragma unroll
    for (int j=0;j<4;++j){ acc[i][j][0]=0.f; acc[i][j][1]=0.f; acc[i][j][2]=0.f; acc[i][j][3]=0.f; }
  for (int kb = 0; kb < 8; ++kb){
    const int K0 = kb * 64;
    #pragma unroll
    for (int i=0;i<4;++i){
      int idx = t + i*256;
      int row = idx >> 3, c8 = (idx & 7) * 8;
      uint4 v; v.x=0u; v.y=0u; v.z=0u; v.w=0u;
      if (m0 + row < M) v = *(const uint4*)(A + (size_t)(m0+row)*512 + K0 + c8);
      *(uint4*)(As + row*72 + c8) = v;
    }
    #pragma unroll
    for (int i=0;i<2;++i){
      int idx = t + i*256;
      int row = idx >> 3, c8 = (idx & 7) * 8;
      *(uint4*)(Bs + row*72 + c8) = *(const uint4*)(Bt + (size_t)row*512 + K0 + c8);
    }
    __syncthreads();
    #pragma unroll
    for (int ks = 0; ks < 2; ++ks){
      short8 af[2], bfr[4];
      #pragma unroll
      for (int mi=0; mi<2; ++mi)
        af[mi] = *(const short8*)(As + (moff + mi*16 + l16)*72 + ks*32 + quad*8);
      #pragma unroll
      for (int ni=0; ni<4; ++ni)
        bfr[ni] = *(const short8*)(Bs + (ni*16 + l16)*72 + ks*32 + quad*8);
      #pragma unroll
      for (int mi=0; mi<2; ++mi)
        #pragma unroll
        for (int ni=0; ni<4; ++ni)
          acc[mi][ni] = __builtin_amdgcn_mfma_f32_16x16x32_bf16(af[mi], bfr[ni], acc[mi][ni], 0,0,0);
    }
    __syncthreads();
  }
  unsigned short* Cs = sm;                       // 128x72 bf16
  #pragma unroll
  for (int mi=0; mi<2; ++mi)
    #pragma unroll
    for (int ni=0; ni<4; ++ni){
      int col = ni*16 + l16;
      int rb  = moff + mi*16 + quad*4;
      #pragma unroll
      for (int r=0;r<4;++r) Cs[(rb+r)*72 + col] = f2bf(acc[mi][ni][r]);
    }
  __syncthreads();
  #pragma unroll
  for (int i=0;i<4;++i){
    int e = t + i*256;
    int row = e >> 3, c8 = (e & 7) * 8;
    if (m0 + row < M)
      *(uint4*)(C + (size_t)(m0+row)*64 + c8) = *(const uint4*)(Cs + row*72 + c8);
  }
  // fused scores: thread pair covers one row (32 cols each)
  {
    int row = t >> 1, half = t & 1;
    const float* alp = al + half*32;
    const float* arp = ar + half*32;
    const unsigned short* cp = Cs + row*72 + half*32;
    float se = 0.f, sr = 0.f;
    #pragma unroll
    for (int i=0;i<4;++i){
      uint4 q = *(const uint4*)(cp + i*8);
      float4 a0 = *(const float4*)(alp + i*8), a1 = *(const float4*)(alp + i*8 + 4);
      float4 r0 = *(const float4*)(arp + i*8), r1 = *(const float4*)(arp + i*8 + 4);
      se += bflo(q.x)*a0.x + bfhi(q.x)*a0.y + bflo(q.y)*a0.z + bfhi(q.y)*a0.w
          + bflo(q.z)*a1.x + bfhi(q.z)*a1.y + bflo(q.w)*a1.z + bfhi(q.w)*a1.w;
      sr += bflo(q.x)*r0.x + bfhi(q.x)*r0.y + bflo(q.y)*r0.z + bfhi(q.y)*r0.w
          + bflo(q.z)*r1.x + bfhi(q.z)*r1.y + bflo(q.w)*r1.z + bfhi(q.w)*r1.w;
    }
    se += __shfl_xor(se, 1); sr += __shfl_xor(sr, 1);
    if (half == 0 && m0 + row < M){
      el[m0+row] = se * LOG2E;   // pre-scale for exp2 weights
      er[m0+row] = sr * LOG2E;
    }
  }
}

// ---- bucketed CSR build ----
__global__ void k_zero(int* __restrict__ p, int n){
  int i = blockIdx.x*blockDim.x + threadIdx.x;
  if (i < n) p[i] = 0;
}
__global__ void k_bcount(const int* __restrict__ dst, int* __restrict__ bcnt){
  int e = blockIdx.x*blockDim.x + threadIdx.x;
  if (e < N_EDGES) atomicAdd(&bcnt[(dst[e] >> 7) * 16], 1);
}
__global__ __launch_bounds__(1024) void k_bscan(const int* __restrict__ bcnt,
    int* __restrict__ bbase, int* __restrict__ bcur){
  __shared__ int lds[1024];
  int t = threadIdx.x;
  int v = (t < NB) ? bcnt[t*16] : 0;
  lds[t] = v; __syncthreads();
  for (int off=1; off<1024; off<<=1){
    int u = (t>=off)? lds[t-off] : 0;
    __syncthreads();
    lds[t] += u;
    __syncthreads();
  }
  if (t < NB){
    int ex = lds[t] - v;            // exclusive prefix
    bbase[t] = ex;
    bcur[t*16] = ex;
  }
  if (t == 0) bbase[NB] = N_EDGES;
}
__global__ void k_bucket(const int* __restrict__ src, const int* __restrict__ dst,
                         int* __restrict__ bcur, int* __restrict__ staged){
  int e = blockIdx.x*blockDim.x + threadIdx.x;
  if (e < N_EDGES){
    int d = dst[e];
    int b = d >> 7;
    int pos = atomicAdd(&bcur[b*16], 1);
    staged[pos] = (src[e] << 7) | (d & (NPB-1));
  }
}
__global__ __launch_bounds__(256) void k_binsort(const int* __restrict__ staged,
    const int* __restrict__ bbase, int* __restrict__ csr_src,
    int* __restrict__ indptr){
  __shared__ int hist[NPB];
  __shared__ int scan[NPB];
  __shared__ int lcur[NPB];
  const int b = blockIdx.x, t = threadIdx.x;
  const int base = bbase[b], end = bbase[b+1];
  if (t < NPB) hist[t] = 0;
  __syncthreads();
  for (int i = base + t; i < end; i += 256)
    atomicAdd(&hist[staged[i] & (NPB-1)], 1);
  __syncthreads();
  int v = (t < NPB) ? hist[t] : 0;
  if (t < NPB) scan[t] = v;
  __syncthreads();
  for (int off=1; off<NPB; off<<=1){
    int u = (t < NPB && t >= off) ? scan[t-off] : 0;
    __syncthreads();
    if (t < NPB) scan[t] += u;
    __syncthreads();
  }
  const int node0 = b * NPB;
  if (t < NPB){
    int ex = base + scan[t] - v;    // global exclusive offset for node0+t
    lcur[t] = ex;
    if (node0 + t < N_NODES) indptr[node0 + t] = ex;
  }
  if (b == NB-1 && t == 0) indptr[N_NODES] = N_EDGES;
  __syncthreads();
  for (int i = base + t; i < end; i += 256){
    int pv = staged[i];
    int pos = atomicAdd(&lcur[pv & (NPB-1)], 1);
    csr_src[pos] = pv >> 7;
  }
}

// ---- layer-1 aggregate + ELU: one-pass softmax, wave per node ----
// 4-edge unroll: 4 independent 512B gathers in flight per wave (MLP depth).
__global__ __launch_bounds__(256) void k_agg1(const unsigned char* __restrict__ feat,
    const float* __restrict__ el, const float* __restrict__ er,
    const int* __restrict__ indptr, const int* __restrict__ csr_src,
    unsigned short* __restrict__ out){
  int wave = threadIdx.x >> 6, lane = threadIdx.x & 63;
  int n = blockIdx.x*4 + wave;
  if (n >= N_NODES) return;
  int p0 = indptr[n], p1 = indptr[n+1];
  const int hh = lane >> 4;
  const unsigned d0 = lane * 8u;
  const float myer = er[n*4 + hh];
  float ssum = 0.f;
  f32x2 acc[4];
  #pragma unroll
  for (int i=0;i<4;++i){ acc[i][0]=0.f; acc[i][1]=0.f; }
  int e = p0;
  for (; e + 3 < p1; e += 4){
    int s0 = csr_src[e], s1 = csr_src[e+1], s2 = csr_src[e+2], s3 = csr_src[e+3];
    // issue all 4 long-latency gathers first
    uint2 q0 = *(const uint2*)(feat + (((unsigned)s0) << 9) + d0);
    uint2 q1 = *(const uint2*)(feat + (((unsigned)s1) << 9) + d0);
    uint2 q2 = *(const uint2*)(feat + (((unsigned)s2) << 9) + d0);
    uint2 q3 = *(const uint2*)(feat + (((unsigned)s3) << 9) + d0);
    float t0 = el[(s0<<2) + hh] + myer;
    float t1 = el[(s1<<2) + hh] + myer;
    float t2 = el[(s2<<2) + hh] + myer;
    float t3 = el[(s3<<2) + hh] + myer;
    float w0 = wexp(t0), w1 = wexp(t1), w2 = wexp(t2), w3 = wexp(t3);
    ssum += (w0 + w1) + (w2 + w3);
    f32x2 W0; W0[0]=w0; W0[1]=w0;
    f32x2 W1; W1[0]=w1; W1[1]=w1;
    f32x2 W2; W2[0]=w2; W2[1]=w2;
    f32x2 W3; W3[0]=w3; W3[1]=w3;
    pk_fma(acc[0], unpk_fp8_lo(q0.x), W0); pk_fma(acc[0], unpk_fp8_lo(q1.x), W1);
    pk_fma(acc[1], unpk_fp8_hi(q0.x), W0); pk_fma(acc[1], unpk_fp8_hi(q1.x), W1);
    pk_fma(acc[2], unpk_fp8_lo(q0.y), W0); pk_fma(acc[2], unpk_fp8_lo(q1.y), W1);
    pk_fma(acc[3], unpk_fp8_hi(q0.y), W0); pk_fma(acc[3], unpk_fp8_hi(q1.y), W1);
    pk_fma(acc[0], unpk_fp8_lo(q2.x), W2); pk_fma(acc[0], unpk_fp8_lo(q3.x), W3);
    pk_fma(acc[1], unpk_fp8_hi(q2.x), W2); pk_fma(acc[1], unpk_fp8_hi(q3.x), W3);
    pk_fma(acc[2], unpk_fp8_lo(q2.y), W2); pk_fma(acc[2], unpk_fp8_lo(q3.y), W3);
    pk_fma(acc[3], unpk_fp8_hi(q2.y), W2); pk_fma(acc[3], unpk_fp8_hi(q3.y), W3);
  }
  for (; e < p1; ++e){
    int s0 = csr_src[e];
    float t0 = el[(s0<<2) + hh] + myer;
    uint2 q0 = *(const uint2*)(feat + (((unsigned)s0) << 9) + d0);
    float w0 = wexp(t0);
    ssum += w0;
    f32x2 W0; W0[0]=w0; W0[1]=w0;
    pk_fma(acc[0], unpk_fp8_lo(q0.x), W0);
    pk_fma(acc[1], unpk_fp8_hi(q0.x), W0);
    pk_fma(acc[2], unpk_fp8_lo(q0.y), W0);
    pk_fma(acc[3], unpk_fp8_hi(q0.y), W0);
  }
  float inv = ssum > 0.f ? 1.f/ssum : 0.f;
  float o8[8] = {acc[0][0],acc[0][1],acc[1][0],acc[1][1],
                 acc[2][0],acc[2][1],acc[3][0],acc[3][1]};
  #pragma unroll
  for (int i=0;i<8;++i){
    float v = o8[i] * inv;
    o8[i] = v > 0.f ? v : __expf(v) - 1.f;   // fused ELU
  }
  uint4 o;
  o.x = packbf(o8[0],o8[1]); o.y = packbf(o8[2],o8[3]);
  o.z = packbf(o8[4],o8[5]); o.w = packbf(o8[6],o8[7]);
  *(uint4*)(out + (size_t)n*512 + d0) = o;
}

// ---- layer-2 aggregate: one-pass, wave per node, eighth-wave per edge ----
__global__ __launch_bounds__(256) void k_agg2(const unsigned short* __restrict__ feat,
    const float* __restrict__ el, const float* __restrict__ er,
    const int* __restrict__ indptr, const int* __restrict__ csr_src,
    float* __restrict__ out){
  int wave = threadIdx.x >> 6, lane = threadIdx.x & 63;
  int n = blockIdx.x*4 + wave;
  if (n >= N_NODES) return;
  int p0 = indptr[n], p1 = indptr[n+1];
  float ern = er[n];
  int g = lane >> 3, ql = lane & 7;
  float s = 0.f;
  f32x2 acc[4];
  #pragma unroll
  for (int i=0;i<4;++i){ acc[i][0]=0.f; acc[i][1]=0.f; }
  for (int e = p0 + g; e < p1; e += 8){
    int si = csr_src[e];
    float w = wexp(el[si] + ern);
    uint4 v = *(const uint4*)(feat + (size_t)si*64 + ql*8);
    s += w;
    f32x2 W; W[0]=w; W[1]=w;
    f32x2 a;
    a[0]=bflo(v.x); a[1]=bfhi(v.x); pk_fma(acc[0], a, W);
    a[0]=bflo(v.y); a[1]=bfhi(v.y); pk_fma(acc[1], a, W);
    a[0]=bflo(v.z); a[1]=bfhi(v.z); pk_fma(acc[2], a, W);
    a[0]=bflo(v.w); a[1]=bfhi(v.w); pk_fma(acc[3], a, W);
  }
  #pragma unroll
  for (int m=8;m<64;m<<=1){
    s += __shfl_xor(s,m);
    #pragma unroll
    for (int i=0;i<4;++i){
      acc[i][0] += __shfl_xor(acc[i][0],m);
      acc[i][1] += __shfl_xor(acc[i][1],m);
    }
  }
  float inv = s > 0.f ? 1.f/s : 0.f;
  if (g == 0){
    float* op = out + (size_t)n*64 + ql*8;
    *(float4*)op     = make_float4(acc[0][0]*inv, acc[0][1]*inv, acc[1][0]*inv, acc[1][1]*inv);
    *(float4*)(op+4) = make_float4(acc[2][0]*inv, acc[2][1]*inv, acc[3][0]*inv, acc[3][1]*inv);
  }
}

extern "C" void kernel_launch(void* const* d_in, const int* in_sizes, int n_in,
                              void* d_out, int out_size, void* d_ws, size_t ws_size,
                              hipStream_t stream){
  const float* x   = (const float*)d_in[0];
  const float* W1  = (const float*)d_in[1];
  const float* al1 = (const float*)d_in[2];
  const float* ar1 = (const float*)d_in[3];
  const float* W2  = (const float*)d_in[4];
  const float* al2 = (const float*)d_in[5];
  const float* ar2 = (const float*)d_in[6];
  const int* src   = (const int*)d_in[7];
  const int* dst   = (const int*)d_in[8];
  float* out = (float*)d_out;

  char* ws = (char*)d_ws;
  size_t off = 0;
  auto alloc = [&](size_t bytes)->char*{
    char* p = ws + off; off += (bytes + 255) & ~(size_t)255; return p;
  };
  unsigned char*  feat1 = (unsigned char*)alloc((size_t)N_NODES*512);     // 51.2 MB fp8
  unsigned short* h1    = (unsigned short*)alloc((size_t)N_NODES*512*2);  // 102.4 MB
  unsigned short* feat2b = (unsigned short*)feat1;  // alias: feat1 dead after k_agg1
  unsigned short* W1t = (unsigned short*)alloc(512*128*2);
  unsigned short* W2t = (unsigned short*)alloc(64*512*2);
  float* el1 = (float*)alloc((size_t)N_NODES*4*4);
  float* er1 = (float*)alloc((size_t)N_NODES*4*4);
  float* el2 = el1;                           // alias: el1 dead after k_agg1
  float* er2 = er1;
  int* bcnt    = (int*)alloc((size_t)NB*16*4);        // padded: 1 counter / 64B
  int* bcur    = (int*)alloc((size_t)NB*16*4);
  int* bbase   = (int*)alloc((size_t)(NB+1)*4);
  int* indptr  = (int*)alloc((size_t)(N_NODES+1)*4);
  int* staged  = (int*)alloc((size_t)N_EDGES*4);                          // 12.8 MB
  int* csr_src = (int*)alloc((size_t)N_EDGES*4);                          // 12.8 MB
  // total ~183 MB (< proven 222 MB footprint)

  dim3 b256(256);
  k_zero<<<dim3((NB*16+255)/256), b256, 0, stream>>>(bcnt, NB*16);
  k_cvtW1<<<dim3(256), b256, 0, stream>>>(W1, W1t);
  k_cvtW2<<<dim3(128), b256, 0, stream>>>(W2, W2t);
  // layer 1 projection (MFMA) + fused scores; feat1 -> fp8
  k_mm1<<<dim3(782, 4), b256, 0, stream>>>(x, W1t, feat1, N_NODES, al1, ar1, el1, er1);
  // bucketed dst-CSR: bucket-count -> scan -> bucket-scatter -> per-bucket sort
  k_bcount<<<dim3((N_EDGES+255)/256), b256, 0, stream>>>(dst, bcnt);
  k_bscan<<<dim3(1), dim3(1024), 0, stream>>>(bcnt, bbase, bcur);
  k_bucket<<<dim3((N_EDGES+255)/256), b256, 0, stream>>>(src, dst, bcur, staged);
  k_binsort<<<dim3(NB), b256, 0, stream>>>(staged, bbase, csr_src, indptr);
  // layer-1 aggregate + ELU (single-pass, fp8 gather)
  k_agg1<<<dim3(25000), b256, 0, stream>>>(feat1, el1, er1, indptr, csr_src, h1);
  // layer 2 (MFMA) + fused scores
  k_mm2<<<dim3(782), b256, 0, stream>>>(h1, W2t, feat2b, N_NODES, al2, ar2, el2, er2);
  k_agg2<<<dim3(25000), b256, 0, stream>>>(feat2b, el2, er2, indptr, csr_src, out);
}

// Round 5
// 724.444 us; speedup vs baseline: 1.2778x; 1.2364x over previous
//
#include <hip/hip_runtime.h>
#include <math.h>

#define N_NODES 100000
#define N_EDGES 3200000
#define NEG 0.2f
#define NPB 128            // nodes per bucket
#define NB  782            // ceil(N_NODES / NPB)
#define CAP 4608           // staging capacity per bucket (mean 4096 + 8 sigma)
#define LOG2E 1.442695041f

typedef __attribute__((ext_vector_type(8))) short short8;
typedef __attribute__((ext_vector_type(4))) float f32x4;
typedef __attribute__((ext_vector_type(2))) float f32x2;

__device__ __forceinline__ float bflo(unsigned int u){
  union { unsigned int i; float f; } v; v.i = u << 16; return v.f;
}
__device__ __forceinline__ float bfhi(unsigned int u){
  union { unsigned int i; float f; } v; v.i = u & 0xffff0000u; return v.f;
}
__device__ __forceinline__ unsigned short f2bf(float f){
  union { float f; unsigned int i; } v; v.f = f;
  unsigned int r = v.i + 0x7fffu + ((v.i >> 16) & 1u);
  return (unsigned short)(r >> 16);
}
__device__ __forceinline__ unsigned int packbf(float lo, float hi){
  return (unsigned int)f2bf(lo) | ((unsigned int)f2bf(hi) << 16);
}
// 4x fp32 -> packed OCP e4m3 dword (HW cvt, gfx950)
__device__ __forceinline__ unsigned int pk_fp8x4(float a, float b, float c, float d){
  int v = 0;
  v = __builtin_amdgcn_cvt_pk_fp8_f32(a, b, v, false);
  v = __builtin_amdgcn_cvt_pk_fp8_f32(c, d, v, true);
  return (unsigned int)v;
}
__device__ __forceinline__ f32x2 unpk_fp8_lo(unsigned int v){
  return __builtin_amdgcn_cvt_pk_f32_fp8((int)v, false);
}
__device__ __forceinline__ f32x2 unpk_fp8_hi(unsigned int v){
  return __builtin_amdgcn_cvt_pk_f32_fp8((int)v, true);
}
// packed dual-f32 FMA: acc.lo += a.lo*w.lo ; acc.hi += a.hi*w.hi
__device__ __forceinline__ void pk_fma(f32x2 &acc, f32x2 a, f32x2 w){
  asm("v_pk_fma_f32 %0, %1, %2, %0" : "+v"(acc) : "v"(a), "v"(w));
}
// weight: exp2(leaky_relu(t)) with t pre-scaled by log2e; fmax form is exact
__device__ __forceinline__ float wexp(float t){
  return __builtin_amdgcn_exp2f(fmaxf(t, NEG * t));
}
// 16 fp8 bytes * w -> 8 packed-f32 accumulators
__device__ __forceinline__ void fma16(f32x2* acc, uint4 q, float w){
  f32x2 W; W[0]=w; W[1]=w;
  pk_fma(acc[0], unpk_fp8_lo(q.x), W);
  pk_fma(acc[1], unpk_fp8_hi(q.x), W);
  pk_fma(acc[2], unpk_fp8_lo(q.y), W);
  pk_fma(acc[3], unpk_fp8_hi(q.y), W);
  pk_fma(acc[4], unpk_fp8_lo(q.z), W);
  pk_fma(acc[5], unpk_fp8_hi(q.z), W);
  pk_fma(acc[6], unpk_fp8_lo(q.w), W);
  pk_fma(acc[7], unpk_fp8_hi(q.w), W);
}

// ---- fused prep: W1^T bf16, W2^T bf16, bucket cursor init ----
__global__ void k_prep(const float* __restrict__ W1, const float* __restrict__ W2,
                       unsigned short* __restrict__ W1t, unsigned short* __restrict__ W2t,
                       int* __restrict__ bcur){
  int i = blockIdx.x*256 + threadIdx.x;
  if (i < 65536){ int n = i >> 7, k = i & 127; W1t[i] = f2bf(W1[k*512 + n]); }
  else if (i < 98304){ int j = i - 65536; int n = j >> 9, k = j & 511; W2t[j] = f2bf(W2[k*64 + n]); }
  else if (i < 98304 + NB){ int b = i - 98304; bcur[b*16] = b*CAP; }
}

// ---- GEMM1 (MFMA) + fused layer-1 scores; feat1 stored as fp8 e4m3 ----
__global__ __launch_bounds__(256) void k_mm1(const float* __restrict__ A,
    const unsigned short* __restrict__ Bt,
    unsigned char* __restrict__ C8, int M,
    const float* __restrict__ al, const float* __restrict__ ar,
    float* __restrict__ el, float* __restrict__ er){
  __shared__ unsigned short sm[18432];          // As 128x72 | Bs 128x72 (36.9 KB)
  unsigned short* As = sm;
  unsigned short* Bs = sm + 9216;
  const int t = threadIdx.x;
  const int w = t >> 6, l = t & 63;
  const int quad = l >> 4, l16 = l & 15;
  const int m0 = blockIdx.x * 128;
  const int head = blockIdx.y;
  const int moff = (w & 1) * 64, noff = (w >> 1) * 64;
  f32x4 acc[4][4];
  #pragma unroll
  for (int i=0;i<4;++i)
    #pragma unroll
    for (int j=0;j<4;++j){ acc[i][j][0]=0.f; acc[i][j][1]=0.f; acc[i][j][2]=0.f; acc[i][j][3]=0.f; }
  for (int kb = 0; kb < 2; ++kb){
    const int K0 = kb * 64;
    #pragma unroll
    for (int i=0;i<8;++i){              // A: 128x64 fp32 -> bf16 LDS
      int idx = t + i*256;
      int row = idx >> 4, c4 = (idx & 15) * 4;
      float4 v = make_float4(0.f,0.f,0.f,0.f);
      if (m0 + row < M) v = *(const float4*)(A + (size_t)(m0+row)*128 + K0 + c4);
      uint2 p; p.x = packbf(v.x, v.y); p.y = packbf(v.z, v.w);
      *(uint2*)(As + row*72 + c4) = p;
    }
    #pragma unroll
    for (int i=0;i<4;++i){              // B: 128x64 bf16 copy
      int idx = t + i*256;
      int row = idx >> 3, c8 = (idx & 7) * 8;
      *(uint4*)(Bs + row*72 + c8) =
        *(const uint4*)(Bt + (size_t)(head*128 + row)*128 + K0 + c8);
    }
    __syncthreads();
    #pragma unroll
    for (int ks = 0; ks < 2; ++ks){
      short8 af[4], bfr[4];
      #pragma unroll
      for (int mi=0; mi<4; ++mi)
        af[mi] = *(const short8*)(As + (moff + mi*16 + l16)*72 + ks*32 + quad*8);
      #pragma unroll
      for (int ni=0; ni<4; ++ni)
        bfr[ni] = *(const short8*)(Bs + (noff + ni*16 + l16)*72 + ks*32 + quad*8);
      #pragma unroll
      for (int mi=0; mi<4; ++mi)
        #pragma unroll
        for (int ni=0; ni<4; ++ni)
          acc[mi][ni] = __builtin_amdgcn_mfma_f32_16x16x32_bf16(af[mi], bfr[ni], acc[mi][ni], 0,0,0);
    }
    __syncthreads();
  }
  // epilogue: bf16 repack via LDS (exact values for scores), fp8 global store
  unsigned short* Cs = sm;                       // 128x136 bf16 (34.8 KB)
  #pragma unroll
  for (int mi=0; mi<4; ++mi)
    #pragma unroll
    for (int ni=0; ni<4; ++ni){
      int col = noff + ni*16 + l16;
      int rb  = moff + mi*16 + quad*4;
      #pragma unroll
      for (int r=0;r<4;++r) Cs[(rb+r)*136 + col] = f2bf(acc[mi][ni][r]);
    }
  __syncthreads();
  const int hcol = head * 128;
  #pragma unroll
  for (int i=0;i<8;++i){                // 128 rows x 128 cols, 8 fp8/thread/iter
    int e = t + i*256;
    int row = e >> 4, c8 = (e & 15) * 8;
    uint4 qb = *(const uint4*)(Cs + row*136 + c8);
    uint2 o;
    o.x = pk_fp8x4(bflo(qb.x), bfhi(qb.x), bflo(qb.y), bfhi(qb.y));
    o.y = pk_fp8x4(bflo(qb.z), bfhi(qb.z), bflo(qb.w), bfhi(qb.w));
    if (m0 + row < M)
      *(uint2*)(C8 + (size_t)(m0+row)*512 + hcol + c8) = o;
  }
  // fused scores: thread pair (t, t^1) covers one row (64 cols each)
  {
    int row = t >> 1, half = t & 1;
    const float* alp = al + head*128 + half*64;
    const float* arp = ar + head*128 + half*64;
    const unsigned short* cp = Cs + row*136 + half*64;
    float se = 0.f, sr = 0.f;
    #pragma unroll
    for (int i=0;i<8;++i){
      uint4 q = *(const uint4*)(cp + i*8);
      float4 a0 = *(const float4*)(alp + i*8), a1 = *(const float4*)(alp + i*8 + 4);
      float4 r0 = *(const float4*)(arp + i*8), r1 = *(const float4*)(arp + i*8 + 4);
      se += bflo(q.x)*a0.x + bfhi(q.x)*a0.y + bflo(q.y)*a0.z + bfhi(q.y)*a0.w
          + bflo(q.z)*a1.x + bfhi(q.z)*a1.y + bflo(q.w)*a1.z + bfhi(q.w)*a1.w;
      sr += bflo(q.x)*r0.x + bfhi(q.x)*r0.y + bflo(q.y)*r0.z + bfhi(q.y)*r0.w
          + bflo(q.z)*r1.x + bfhi(q.z)*r1.y + bflo(q.w)*r1.z + bfhi(q.w)*r1.w;
    }
    se += __shfl_xor(se, 1); sr += __shfl_xor(sr, 1);
    if (half == 0 && m0 + row < M){
      el[(m0+row)*4 + head] = se * LOG2E;   // pre-scale for exp2 weights
      er[(m0+row)*4 + head] = sr * LOG2E;
    }
  }
}

// ---- GEMM2 (MFMA) + fused layer-2 scores ----
__global__ __launch_bounds__(256) void k_mm2(const unsigned short* __restrict__ A,
    const unsigned short* __restrict__ Bt,
    unsigned short* __restrict__ C, int M,
    const float* __restrict__ al, const float* __restrict__ ar,
    float* __restrict__ el, float* __restrict__ er){
  __shared__ unsigned short sm[13824];          // As 128x72 | Bs 64x72 (27.6 KB)
  unsigned short* As = sm;
  unsigned short* Bs = sm + 9216;
  const int t = threadIdx.x;
  const int w = t >> 6, l = t & 63;
  const int quad = l >> 4, l16 = l & 15;
  const int m0 = blockIdx.x * 128;
  const int moff = w * 32;
  f32x4 acc[2][4];
  #pragma unroll
  for (int i=0;i<2;++i)
    #pragma unroll
    for (int j=0;j<4;++j){ acc[i][j][0]=0.f; acc[i][j][1]=0.f; acc[i][j][2]=0.f; acc[i][j][3]=0.f; }
  for (int kb = 0; kb < 8; ++kb){
    const int K0 = kb * 64;
    #pragma unroll
    for (int i=0;i<4;++i){
      int idx = t + i*256;
      int row = idx >> 3, c8 = (idx & 7) * 8;
      uint4 v; v.x=0u; v.y=0u; v.z=0u; v.w=0u;
      if (m0 + row < M) v = *(const uint4*)(A + (size_t)(m0+row)*512 + K0 + c8);
      *(uint4*)(As + row*72 + c8) = v;
    }
    #pragma unroll
    for (int i=0;i<2;++i){
      int idx = t + i*256;
      int row = idx >> 3, c8 = (idx & 7) * 8;
      *(uint4*)(Bs + row*72 + c8) = *(const uint4*)(Bt + (size_t)row*512 + K0 + c8);
    }
    __syncthreads();
    #pragma unroll
    for (int ks = 0; ks < 2; ++ks){
      short8 af[2], bfr[4];
      #pragma unroll
      for (int mi=0; mi<2; ++mi)
        af[mi] = *(const short8*)(As + (moff + mi*16 + l16)*72 + ks*32 + quad*8);
      #pragma unroll
      for (int ni=0; ni<4; ++ni)
        bfr[ni] = *(const short8*)(Bs + (ni*16 + l16)*72 + ks*32 + quad*8);
      #pragma unroll
      for (int mi=0; mi<2; ++mi)
        #pragma unroll
        for (int ni=0; ni<4; ++ni)
          acc[mi][ni] = __builtin_amdgcn_mfma_f32_16x16x32_bf16(af[mi], bfr[ni], acc[mi][ni], 0,0,0);
    }
    __syncthreads();
  }
  unsigned short* Cs = sm;                       // 128x72 bf16
  #pragma unroll
  for (int mi=0; mi<2; ++mi)
    #pragma unroll
    for (int ni=0; ni<4; ++ni){
      int col = ni*16 + l16;
      int rb  = moff + mi*16 + quad*4;
      #pragma unroll
      for (int r=0;r<4;++r) Cs[(rb+r)*72 + col] = f2bf(acc[mi][ni][r]);
    }
  __syncthreads();
  #pragma unroll
  for (int i=0;i<4;++i){
    int e = t + i*256;
    int row = e >> 3, c8 = (e & 7) * 8;
    if (m0 + row < M)
      *(uint4*)(C + (size_t)(m0+row)*64 + c8) = *(const uint4*)(Cs + row*72 + c8);
  }
  // fused scores: thread pair covers one row (32 cols each)
  {
    int row = t >> 1, half = t & 1;
    const float* alp = al + half*32;
    const float* arp = ar + half*32;
    const unsigned short* cp = Cs + row*72 + half*32;
    float se = 0.f, sr = 0.f;
    #pragma unroll
    for (int i=0;i<4;++i){
      uint4 q = *(const uint4*)(cp + i*8);
      float4 a0 = *(const float4*)(alp + i*8), a1 = *(const float4*)(alp + i*8 + 4);
      float4 r0 = *(const float4*)(arp + i*8), r1 = *(const float4*)(arp + i*8 + 4);
      se += bflo(q.x)*a0.x + bfhi(q.x)*a0.y + bflo(q.y)*a0.z + bfhi(q.y)*a0.w
          + bflo(q.z)*a1.x + bfhi(q.z)*a1.y + bflo(q.w)*a1.z + bfhi(q.w)*a1.w;
      sr += bflo(q.x)*r0.x + bfhi(q.x)*r0.y + bflo(q.y)*r0.z + bfhi(q.y)*r0.w
          + bflo(q.z)*r1.x + bfhi(q.z)*r1.y + bflo(q.w)*r1.z + bfhi(q.w)*r1.w;
    }
    se += __shfl_xor(se, 1); sr += __shfl_xor(sr, 1);
    if (half == 0 && m0 + row < M){
      el[m0+row] = se * LOG2E;   // pre-scale for exp2 weights
      er[m0+row] = sr * LOG2E;
    }
  }
}

// ---- bucketed CSR build (fixed-capacity staging; no count pass) ----
__global__ void k_bucket(const int* __restrict__ src, const int* __restrict__ dst,
                         int* __restrict__ bcur, int* __restrict__ staged){
  int e = blockIdx.x*blockDim.x + threadIdx.x;
  if (e < N_EDGES){
    int d = dst[e];
    int b = d >> 7;
    int pos = atomicAdd(&bcur[b*16], 1);
    staged[pos] = (src[e] << 7) | (d & (NPB-1));
  }
}
__global__ __launch_bounds__(1024) void k_bscan(const int* __restrict__ bcur,
    int* __restrict__ bbase){
  __shared__ int lds[1024];
  int t = threadIdx.x;
  int v = (t < NB) ? (bcur[t*16] - t*CAP) : 0;
  lds[t] = v; __syncthreads();
  for (int off=1; off<1024; off<<=1){
    int u = (t>=off)? lds[t-off] : 0;
    __syncthreads();
    lds[t] += u;
    __syncthreads();
  }
  if (t < NB) bbase[t] = lds[t] - v;   // exclusive prefix
  if (t == 0) bbase[NB] = N_EDGES;
}
__global__ __launch_bounds__(256) void k_binsort(const int* __restrict__ staged,
    const int* __restrict__ bcur, const int* __restrict__ bbase,
    int* __restrict__ csr_src, int* __restrict__ indptr){
  __shared__ int hist[NPB];
  __shared__ int scan[NPB];
  __shared__ int lcur[NPB];
  const int b = blockIdx.x, t = threadIdx.x;
  const int st0 = b*CAP;
  const int cnt = bcur[b*16] - st0;
  const int obase = bbase[b];
  if (t < NPB) hist[t] = 0;
  __syncthreads();
  for (int i = t; i < cnt; i += 256)
    atomicAdd(&hist[staged[st0 + i] & (NPB-1)], 1);
  __syncthreads();
  int v = (t < NPB) ? hist[t] : 0;
  if (t < NPB) scan[t] = v;
  __syncthreads();
  for (int off=1; off<NPB; off<<=1){
    int u = (t < NPB && t >= off) ? scan[t-off] : 0;
    __syncthreads();
    if (t < NPB) scan[t] += u;
    __syncthreads();
  }
  const int node0 = b * NPB;
  if (t < NPB){
    int ex = obase + scan[t] - v;    // global exclusive offset for node0+t
    lcur[t] = ex;
    if (node0 + t < N_NODES) indptr[node0 + t] = ex;
  }
  if (b == NB-1 && t == 0) indptr[N_NODES] = N_EDGES;
  __syncthreads();
  for (int i = t; i < cnt; i += 256){
    int pv = staged[st0 + i];
    int pos = atomicAdd(&lcur[pv & (NPB-1)], 1);
    csr_src[pos] = pv >> 7;
  }
}

// ---- layer-1 aggregate + ELU: half-wave per edge (32 lanes x 16B = 512B row) ----
// 4 loads in flight cover 8 edges; halves combined once per node via shfl_xor(32).
__global__ __launch_bounds__(256) void k_agg1(const unsigned char* __restrict__ feat,
    const float* __restrict__ el, const float* __restrict__ er,
    const int* __restrict__ indptr, const int* __restrict__ csr_src,
    unsigned short* __restrict__ out){
  int wave = threadIdx.x >> 6, lane = threadIdx.x & 63;
  int n = blockIdx.x*4 + wave;
  if (n >= N_NODES) return;
  int p0 = indptr[n], p1 = indptr[n+1];
  const int half = lane >> 5, hl = lane & 31;
  const int hh = hl >> 3;                 // head = (hl*16)/128
  const unsigned d0 = hl * 16u;           // byte offset in 512B row
  const float myer = er[n*4 + hh];
  float ssum = 0.f;
  f32x2 acc[8];
  #pragma unroll
  for (int i=0;i<8;++i){ acc[i][0]=0.f; acc[i][1]=0.f; }
  int e = p0;
  for (; e + 7 < p1; e += 8){
    int s0 = csr_src[e + 0 + half];
    int s1 = csr_src[e + 2 + half];
    int s2 = csr_src[e + 4 + half];
    int s3 = csr_src[e + 6 + half];
    uint4 q0 = *(const uint4*)(feat + (((unsigned)s0) << 9) + d0);
    uint4 q1 = *(const uint4*)(feat + (((unsigned)s1) << 9) + d0);
    uint4 q2 = *(const uint4*)(feat + (((unsigned)s2) << 9) + d0);
    uint4 q3 = *(const uint4*)(feat + (((unsigned)s3) << 9) + d0);
    float t0 = el[(s0<<2) + hh] + myer;
    float t1 = el[(s1<<2) + hh] + myer;
    float t2 = el[(s2<<2) + hh] + myer;
    float t3 = el[(s3<<2) + hh] + myer;
    float w0 = wexp(t0), w1 = wexp(t1), w2 = wexp(t2), w3 = wexp(t3);
    ssum += (w0 + w1) + (w2 + w3);
    fma16(acc, q0, w0);
    fma16(acc, q1, w1);
    fma16(acc, q2, w2);
    fma16(acc, q3, w3);
  }
  for (; e < p1; e += 2){
    int idx = e + half;
    bool ok = idx < p1;
    int s = csr_src[ok ? idx : e];
    uint4 q = *(const uint4*)(feat + (((unsigned)s) << 9) + d0);
    float w = ok ? wexp(el[(s<<2) + hh] + myer) : 0.f;
    ssum += w;
    fma16(acc, q, w);
  }
  // combine the two halves (same dims, disjoint edge subsets)
  ssum += __shfl_xor(ssum, 32);
  float o16[16];
  #pragma unroll
  for (int i=0;i<8;++i){
    o16[2*i]   = acc[i][0] + __shfl_xor(acc[i][0], 32);
    o16[2*i+1] = acc[i][1] + __shfl_xor(acc[i][1], 32);
  }
  float inv = ssum > 0.f ? 1.f/ssum : 0.f;
  #pragma unroll
  for (int i=0;i<16;++i){
    float v = o16[i] * inv;
    o16[i] = v > 0.f ? v : __expf(v) - 1.f;   // fused ELU
  }
  if (half == 0){
    unsigned short* op = out + (size_t)n*512 + hl*16;
    uint4 oa, ob;
    oa.x = packbf(o16[0], o16[1]);  oa.y = packbf(o16[2], o16[3]);
    oa.z = packbf(o16[4], o16[5]);  oa.w = packbf(o16[6], o16[7]);
    ob.x = packbf(o16[8], o16[9]);  ob.y = packbf(o16[10],o16[11]);
    ob.z = packbf(o16[12],o16[13]); ob.w = packbf(o16[14],o16[15]);
    *(uint4*)op       = oa;
    *(uint4*)(op + 8) = ob;
  }
}

// ---- layer-2 aggregate: eighth-wave per edge, 2-edge unroll ----
__global__ __launch_bounds__(256) void k_agg2(const unsigned short* __restrict__ feat,
    const float* __restrict__ el, const float* __restrict__ er,
    const int* __restrict__ indptr, const int* __restrict__ csr_src,
    float* __restrict__ out){
  int wave = threadIdx.x >> 6, lane = threadIdx.x & 63;
  int n = blockIdx.x*4 + wave;
  if (n >= N_NODES) return;
  int p0 = indptr[n], p1 = indptr[n+1];
  float ern = er[n];
  int g = lane >> 3, ql = lane & 7;
  float s = 0.f;
  f32x2 acc[4];
  #pragma unroll
  for (int i=0;i<4;++i){ acc[i][0]=0.f; acc[i][1]=0.f; }
  int e = p0 + g;
  for (; e + 8 < p1; e += 16){
    int sa = csr_src[e], sb = csr_src[e+8];
    uint4 va = *(const uint4*)(feat + (size_t)sa*64 + ql*8);
    uint4 vb = *(const uint4*)(feat + (size_t)sb*64 + ql*8);
    float wa = wexp(el[sa] + ern);
    float wb = wexp(el[sb] + ern);
    s += wa + wb;
    f32x2 Wa; Wa[0]=wa; Wa[1]=wa;
    f32x2 Wb; Wb[0]=wb; Wb[1]=wb;
    f32x2 a;
    a[0]=bflo(va.x); a[1]=bfhi(va.x); pk_fma(acc[0], a, Wa);
    a[0]=bflo(va.y); a[1]=bfhi(va.y); pk_fma(acc[1], a, Wa);
    a[0]=bflo(va.z); a[1]=bfhi(va.z); pk_fma(acc[2], a, Wa);
    a[0]=bflo(va.w); a[1]=bfhi(va.w); pk_fma(acc[3], a, Wa);
    a[0]=bflo(vb.x); a[1]=bfhi(vb.x); pk_fma(acc[0], a, Wb);
    a[0]=bflo(vb.y); a[1]=bfhi(vb.y); pk_fma(acc[1], a, Wb);
    a[0]=bflo(vb.z); a[1]=bfhi(vb.z); pk_fma(acc[2], a, Wb);
    a[0]=bflo(vb.w); a[1]=bfhi(vb.w); pk_fma(acc[3], a, Wb);
  }
  for (; e < p1; e += 8){
    int si = csr_src[e];
    float w = wexp(el[si] + ern);
    uint4 v = *(const uint4*)(feat + (size_t)si*64 + ql*8);
    s += w;
    f32x2 W; W[0]=w; W[1]=w;
    f32x2 a;
    a[0]=bflo(v.x); a[1]=bfhi(v.x); pk_fma(acc[0], a, W);
    a[0]=bflo(v.y); a[1]=bfhi(v.y); pk_fma(acc[1], a, W);
    a[0]=bflo(v.z); a[1]=bfhi(v.z); pk_fma(acc[2], a, W);
    a[0]=bflo(v.w); a[1]=bfhi(v.w); pk_fma(acc[3], a, W);
  }
  #pragma unroll
  for (int m=8;m<64;m<<=1){
    s += __shfl_xor(s,m);
    #pragma unroll
    for (int i=0;i<4;++i){
      acc[i][0] += __shfl_xor(acc[i][0],m);
      acc[i][1] += __shfl_xor(acc[i][1],m);
    }
  }
  float inv = s > 0.f ? 1.f/s : 0.f;
  if (g == 0){
    float* op = out + (size_t)n*64 + ql*8;
    *(float4*)op     = make_float4(acc[0][0]*inv, acc[0][1]*inv, acc[1][0]*inv, acc[1][1]*inv);
    *(float4*)(op+4) = make_float4(acc[2][0]*inv, acc[2][1]*inv, acc[3][0]*inv, acc[3][1]*inv);
  }
}

extern "C" void kernel_launch(void* const* d_in, const int* in_sizes, int n_in,
                              void* d_out, int out_size, void* d_ws, size_t ws_size,
                              hipStream_t stream){
  const float* x   = (const float*)d_in[0];
  const float* W1  = (const float*)d_in[1];
  const float* al1 = (const float*)d_in[2];
  const float* ar1 = (const float*)d_in[3];
  const float* W2  = (const float*)d_in[4];
  const float* al2 = (const float*)d_in[5];
  const float* ar2 = (const float*)d_in[6];
  const int* src   = (const int*)d_in[7];
  const int* dst   = (const int*)d_in[8];
  float* out = (float*)d_out;

  char* ws = (char*)d_ws;
  size_t off = 0;
  auto alloc = [&](size_t bytes)->char*{
    char* p = ws + off; off += (bytes + 255) & ~(size_t)255; return p;
  };
  unsigned char*  feat1 = (unsigned char*)alloc((size_t)N_NODES*512);     // 51.2 MB fp8
  unsigned short* h1    = (unsigned short*)alloc((size_t)N_NODES*512*2);  // 102.4 MB
  unsigned short* feat2b = (unsigned short*)feat1;  // alias: feat1 dead after k_agg1
  unsigned short* W1t = (unsigned short*)alloc(512*128*2);
  unsigned short* W2t = (unsigned short*)alloc(64*512*2);
  float* el1 = (float*)alloc((size_t)N_NODES*4*4);
  float* er1 = (float*)alloc((size_t)N_NODES*4*4);
  float* el2 = el1;                           // alias: el1 dead after k_agg1
  float* er2 = er1;
  int* bcur    = (int*)alloc((size_t)NB*16*4);        // padded: 1 counter / 64B
  int* bbase   = (int*)alloc((size_t)(NB+1)*4);
  int* indptr  = (int*)alloc((size_t)(N_NODES+1)*4);
  int* staged  = (int*)alloc((size_t)NB*CAP*4);                           // 14.4 MB
  int* csr_src = (int*)alloc((size_t)N_EDGES*4);                          // 12.8 MB
  // total ~185 MB (< proven 222 MB footprint)

  dim3 b256(256);
  // prep: W1t, W2t, bucket cursors (one launch)
  k_prep<<<dim3(388), b256, 0, stream>>>(W1, W2, W1t, W2t, bcur);
  // layer 1 projection (MFMA) + fused scores; feat1 -> fp8
  k_mm1<<<dim3(782, 4), b256, 0, stream>>>(x, W1t, feat1, N_NODES, al1, ar1, el1, er1);
  // bucketed dst-CSR: scatter into fixed-capacity buckets -> scan -> per-bucket sort
  k_bucket<<<dim3((N_EDGES+255)/256), b256, 0, stream>>>(src, dst, bcur, staged);
  k_bscan<<<dim3(1), dim3(1024), 0, stream>>>(bcur, bbase);
  k_binsort<<<dim3(NB), b256, 0, stream>>>(staged, bcur, bbase, csr_src, indptr);
  // layer-1 aggregate + ELU (single-pass, fp8 gather, half-wave per edge)
  k_agg1<<<dim3(25000), b256, 0, stream>>>(feat1, el1, er1, indptr, csr_src, h1);
  // layer 2 (MFMA) + fused scores
  k_mm2<<<dim3(782), b256, 0, stream>>>(h1, W2t, feat2b, N_NODES, al2, ar2, el2, er2);
  k_agg2<<<dim3(25000), b256, 0, stream>>>(feat2b, el2, er2, indptr, csr_src, out);
}